// Round 3
// baseline (213.889 us; speedup 1.0000x reference)
//
#include <hip/hip_runtime.h>
#include <hip/hip_bf16.h>

// VectorQuantizer: x [32768 x 64] fp32, e [64 x 1024] fp32.
// d_out = [out (2097152 f32) = x + (q-x), loss = 1.25*mean((q-x)^2)].
//
// R3: wave-owns-16-rows MFMA scan, zero LDS / zero barriers in vq_main,
// register double-prefetch of B, shfl-butterfly argmin. Ambiguous rows
// (best2-best < MARGIN) compacted to a list; vq_fix re-scores them exactly
// in fp32 (R1-validated formula/order) and finalizes the loss.

#define NROWS 32768
#define DDIM  64
#define KCODE 1024
#define NELEM (NROWS * DDIM)
#define MARGIN 5e-4f
#define FIXBLOCKS 64

typedef __attribute__((ext_vector_type(8))) short bf16x8;
typedef __attribute__((ext_vector_type(4))) float f32x4;

static __device__ __forceinline__ unsigned short f2bf(float v) {
    __hip_bfloat16 h = __float2bfloat16(v);
    unsigned short b;
    __builtin_memcpy(&b, &h, 2);
    return b;
}
static __device__ __forceinline__ float bf2f(unsigned short b) {
    unsigned int u = ((unsigned int)b) << 16;
    float f;
    __builtin_memcpy(&f, &u, 4);
    return f;
}

// ---------------------------------------------------------------------------
// prep: se[k] exact fp32 (ascending-d fmaf, matches fix), eT[k][d] fp32,
// ehT/elT[k][d] bf16 hi/lo. Also zeroes ctrl words (loss, cnt, done).
__global__ void vq_prep(const float* __restrict__ e,
                        float* __restrict__ se,
                        float* __restrict__ eT,
                        unsigned short* __restrict__ ehT,
                        unsigned short* __restrict__ elT,
                        int* __restrict__ ctrl) {
    __shared__ float tile[64][65];
    const int t = threadIdx.x;
    const int k0 = blockIdx.x * 64;
    if (blockIdx.x == 0 && t < 4) ctrl[t] = 0;
    #pragma unroll
    for (int i = 0; i < 16; ++i) {
        int idx = i * 256 + t;
        int d = idx >> 6, kk = idx & 63;
        tile[d][kk] = e[d * KCODE + k0 + kk];
    }
    __syncthreads();
    if (t < 64) {
        float s = 0.f;
        #pragma unroll
        for (int d = 0; d < 64; ++d) { float v = tile[d][t]; s = fmaf(v, v, s); }
        se[k0 + t] = s;
    }
    const int kk = t >> 2, dg = (t & 3) * 16;
    const int kg = k0 + kk;
    #pragma unroll
    for (int d = dg; d < dg + 16; ++d) {
        float v = tile[d][kk];
        eT[(size_t)kg * 64 + d] = v;
        unsigned short hb = f2bf(v);
        ehT[(size_t)kg * 64 + d] = hb;
        elT[(size_t)kg * 64 + d] = f2bf(v - bf2f(hb));
    }
}

// ---------------------------------------------------------------------------
__launch_bounds__(256)
__global__ void vq_main(const float* __restrict__ x,
                        const float* __restrict__ se,
                        const float* __restrict__ eT,
                        const unsigned short* __restrict__ ehT,
                        const unsigned short* __restrict__ elT,
                        float* __restrict__ out,
                        float* __restrict__ lossAcc,
                        int* __restrict__ cnt,
                        int2* __restrict__ list) {
    const int t = threadIdx.x;
    const int lane = t & 63;
    const int w = t >> 6;
    const int quad = lane >> 4, l15 = lane & 15;
    const int rowBase = blockIdx.x * 64 + w * 16;   // this wave's 16 rows

    // ---- A fragments from global (row = l15, k = quad*8 + ks*32 + j) ----
    bf16x8 ah[2], al[2];
    #pragma unroll
    for (int ks = 0; ks < 2; ++ks) {
        const float4* ap = (const float4*)(x + (size_t)(rowBase + l15) * 64 + ks * 32 + quad * 8);
        float4 a0 = ap[0], a1 = ap[1];
        float av[8] = {a0.x, a0.y, a0.z, a0.w, a1.x, a1.y, a1.z, a1.w};
        bf16x8 h, l;
        #pragma unroll
        for (int j = 0; j < 8; ++j) {
            unsigned short hb = f2bf(av[j]);
            h[j] = (short)hb;
            l[j] = (short)f2bf(av[j] - bf2f(hb));
        }
        ah[ks] = h; al[ks] = l;
    }

    float sb[4], sb2[4];
    int si[4];
    #pragma unroll
    for (int r = 0; r < 4; ++r) { sb[r] = 3.4e38f; sb2[r] = 3.4e38f; si[r] = 0; }

    // ---- B stream: register prefetch depth 2 (pad tiles 64,65 exist in ws) ----
    const size_t bOff = (size_t)l15 * 64 + quad * 8;
    bf16x8 h0[2], h1[2], l0[2], l1[2];
    float sen[2];
    #pragma unroll
    for (int p = 0; p < 2; ++p) {
        const bf16x8* hp = (const bf16x8*)(ehT + (size_t)p * 1024 + bOff);
        const bf16x8* lp = (const bf16x8*)(elT + (size_t)p * 1024 + bOff);
        h0[p] = hp[0]; h1[p] = hp[4]; l0[p] = lp[0]; l1[p] = lp[4];
        sen[p] = se[p * 16 + l15];
    }

    #pragma unroll 2
    for (int nt = 0; nt < 64; ++nt) {
        const int p = nt & 1;
        bf16x8 ch0 = h0[p], ch1 = h1[p], cl0 = l0[p], cl1 = l1[p];
        float cse = sen[p];
        {   // prefetch tile nt+2 into the slot just freed
            const bf16x8* hp = (const bf16x8*)(ehT + (size_t)(nt + 2) * 1024 + bOff);
            const bf16x8* lp = (const bf16x8*)(elT + (size_t)(nt + 2) * 1024 + bOff);
            h0[p] = hp[0]; h1[p] = hp[4]; l0[p] = lp[0]; l1[p] = lp[4];
            sen[p] = se[(nt + 2) * 16 + l15];
        }
        // two independent 3-MFMA chains (xh*eh + xh*el + xl*eh, split over ks)
        f32x4 aA = {0.f, 0.f, 0.f, 0.f}, aB = {0.f, 0.f, 0.f, 0.f};
        aA = __builtin_amdgcn_mfma_f32_16x16x32_bf16(ah[0], ch0, aA, 0, 0, 0);
        aB = __builtin_amdgcn_mfma_f32_16x16x32_bf16(ah[1], ch1, aB, 0, 0, 0);
        aA = __builtin_amdgcn_mfma_f32_16x16x32_bf16(ah[0], cl0, aA, 0, 0, 0);
        aB = __builtin_amdgcn_mfma_f32_16x16x32_bf16(ah[1], cl1, aB, 0, 0, 0);
        aA = __builtin_amdgcn_mfma_f32_16x16x32_bf16(al[0], ch0, aA, 0, 0, 0);
        aB = __builtin_amdgcn_mfma_f32_16x16x32_bf16(al[1], ch1, aB, 0, 0, 0);
        const int nl = nt * 16 + l15;
        #pragma unroll
        for (int r = 0; r < 4; ++r) {
            float key = fmaf(-2.f, aA[r] + aB[r], cse);   // se - 2*dot
            bool lt = key < sb[r];                        // strict: earliest k wins
            sb2[r] = fminf(sb2[r], fmaxf(sb[r], key));
            sb[r]  = fminf(sb[r], key);
            si[r]  = lt ? nl : si[r];
        }
    }

    // ---- butterfly argmin across the 16 lanes of each quad (no LDS) ----
    #pragma unroll
    for (int m = 1; m < 16; m <<= 1) {
        #pragma unroll
        for (int r = 0; r < 4; ++r) {
            float ob  = __shfl_xor(sb[r],  m, 64);
            float ob2 = __shfl_xor(sb2[r], m, 64);
            int   oi  = __shfl_xor(si[r],  m, 64);
            float nb2 = fminf(fminf(sb2[r], ob2), fmaxf(sb[r], ob));
            bool take = (ob < sb[r]) || (ob == sb[r] && oi < si[r]);
            sb[r] = take ? ob : sb[r];
            si[r] = take ? oi : si[r];
            sb2[r] = nb2;
        }
    }

    // ---- flag ambiguous rows (rare) ----
    if (l15 == 0) {
        #pragma unroll
        for (int r = 0; r < 4; ++r) {
            if (sb2[r] - sb[r] < MARGIN) {
                int p = atomicAdd(cnt, 1);
                list[p] = make_int2(rowBase + quad * 4 + r, si[r]);
            }
        }
    }

    // ---- broadcast each row's idx to its epilogue lanes via shfl ----
    int src = (l15 >> 2) << 4;             // a lane in quad (l15>>2), l15==0
    int j0 = __shfl(si[0], src, 64);
    int j1 = __shfl(si[1], src, 64);
    int j2 = __shfl(si[2], src, 64);
    int j3 = __shfl(si[3], src, 64);
    int rsel = l15 & 3;
    int myidx = rsel == 0 ? j0 : (rsel == 1 ? j1 : (rsel == 2 ? j2 : j3));

    // ---- epilogue: lane handles row (rowBase+l15), elems [quad*16, quad*16+16) ----
    const float4* qrow = (const float4*)(eT + (size_t)myidx * 64 + quad * 16);
    const float4* xrow = (const float4*)(x + (size_t)(rowBase + l15) * 64 + quad * 16);
    float4* orow = (float4*)(out + (size_t)(rowBase + l15) * 64 + quad * 16);
    float lsum = 0.f;
    #pragma unroll
    for (int i = 0; i < 4; ++i) {
        float4 q = qrow[i];
        float4 xv = xrow[i];
        float4 o;
        float dx;
        dx = q.x - xv.x; o.x = xv.x + dx; lsum = fmaf(dx, dx, lsum);
        dx = q.y - xv.y; o.y = xv.y + dx; lsum = fmaf(dx, dx, lsum);
        dx = q.z - xv.z; o.z = xv.z + dx; lsum = fmaf(dx, dx, lsum);
        dx = q.w - xv.w; o.w = xv.w + dx; lsum = fmaf(dx, dx, lsum);
        orow[i] = o;
    }
    #pragma unroll
    for (int off = 32; off > 0; off >>= 1)
        lsum += __shfl_down(lsum, off, 64);
    if (lane == 0) atomicAdd(lossAcc, lsum);
}

// ---------------------------------------------------------------------------
// Exact fp32 re-score of flagged rows (replicates R1's absmax-0 math), patch
// out + loss; last block finalizes the loss scalar.
__global__ void vq_fix(const float* __restrict__ x,
                       const float* __restrict__ se,
                       const float* __restrict__ eT,
                       const int2* __restrict__ list,
                       const int* __restrict__ cnt,
                       float* __restrict__ lossAcc,
                       int* __restrict__ done,
                       float* __restrict__ out) {
    __shared__ float xs[64];
    __shared__ float cb[256];
    __shared__ int   ci[256];
    __shared__ int   newIdxS;
    const int t = threadIdx.x;
    const int n = *cnt;

    for (int i = blockIdx.x; i < n; i += gridDim.x) {
        int2 en = list[i];
        const int row = en.x, oldIdx = en.y;
        if (t < 64) xs[t] = x[(size_t)row * 64 + t];
        __syncthreads();

        float sx = 0.f;
        #pragma unroll
        for (int d = 0; d < 64; ++d) sx = fmaf(xs[d], xs[d], sx);

        float db = 3.4e38f; int di = 0;
        #pragma unroll
        for (int j = 0; j < 4; ++j) {
            int k = t * 4 + j;
            const float* ep = eT + (size_t)k * 64;
            float dot = 0.f;
            for (int d = 0; d < 64; ++d) dot = fmaf(xs[d], ep[d], dot);
            float t0 = sx + se[k];
            float dd = t0 - 2.0f * dot;                 // exact ref formula
            if (dd < db) { db = dd; di = k; }
        }
        cb[t] = db; ci[t] = di;
        __syncthreads();
        if (t == 0) {
            float B = cb[0]; int I = ci[0];
            for (int c = 1; c < 256; ++c)
                if (cb[c] < B) { B = cb[c]; I = ci[c]; }   // ascending k blocks
            newIdxS = I;
        }
        __syncthreads();

        const int ni = newIdxS;
        if (ni != oldIdx) {
            float delta = 0.f;
            if (t < 64) {
                float xv = xs[t];
                float qn = eT[(size_t)ni * 64 + t];
                float qo = eT[(size_t)oldIdx * 64 + t];
                float dn = qn - xv, dl = qo - xv;
                out[(size_t)row * 64 + t] = xv + dn;
                delta = dn * dn - dl * dl;
                #pragma unroll
                for (int off = 32; off > 0; off >>= 1)
                    delta += __shfl_down(delta, off, 64);
                if (t == 0) atomicAdd(lossAcc, delta);
            }
        }
        __syncthreads();
    }

    if (t == 0) {
        __threadfence();
        int fin = atomicAdd(done, 1);
        if (fin == gridDim.x - 1) {
            float s = atomicAdd(lossAcc, 0.0f);   // ordered read of final sum
            float m = s / (float)NELEM;
            out[NELEM] = 0.25f * m + m;
        }
    }
}

// ---------------------------------------------------------------------------
extern "C" void kernel_launch(void* const* d_in, const int* in_sizes, int n_in,
                              void* d_out, int out_size, void* d_ws, size_t ws_size,
                              hipStream_t stream) {
    const float* x = (const float*)d_in[0];
    const float* e = (const float*)d_in[1];
    float* out = (float*)d_out;
    float* ws  = (float*)d_ws;

    // ws layout (float offsets):
    //   [0..3]   ctrl: lossAcc, cnt, done, spare
    //   +64      se   [1024 + pad]
    //   +2048    eT   [65536]
    //   +67584   ehT  [67584 ushort = 65536 + 2048 pad]
    //   +101376  elT  [67584 ushort]
    //   +135168  list [32768 int2]
    float* lossAcc      = ws;
    int*   cnt          = (int*)(ws + 1);
    int*   done         = (int*)(ws + 2);
    float* se           = ws + 64;
    float* eT           = ws + 2048;
    unsigned short* ehT = (unsigned short*)(ws + 67584);
    unsigned short* elT = (unsigned short*)(ws + 101376);
    int2*  list         = (int2*)(ws + 135168);

    vq_prep<<<16, 256, 0, stream>>>(e, se, eT, ehT, elT, (int*)ws);
    vq_main<<<NROWS / 64, 256, 0, stream>>>(x, se, eT, ehT, elT, out, lossAcc, cnt, list);
    vq_fix<<<FIXBLOCKS, 256, 0, stream>>>(x, se, eT, list, cnt, lossAcc, done, out);
}

// Round 4
// 139.233 us; speedup vs baseline: 1.5362x; 1.5362x over previous
//
#include <hip/hip_runtime.h>
#include <hip/hip_bf16.h>

// VectorQuantizer: x [32768 x 64] fp32, e [64 x 1024] fp32.
// d_out = [out (2097152 f32) = x + (q-x), loss = 1.25*mean((q-x)^2)].
//
// R4: block owns 64 rows (4 MFMA M-tiles shared by 4 waves); each wave scans a
// 256-code K-slice (16 iters) with ring-4 register prefetch of B (bf16 hi/lo).
// One LDS exchange + barrier combines (best,best2,idx) across waves. Ambiguous
// rows (gap < MARGIN) re-scored exactly in fp32 by vq_fix (R1-validated math).

#define NROWS 32768
#define DDIM  64
#define KCODE 1024
#define NELEM (NROWS * DDIM)
#define MARGIN 2.5e-4f
#define FIXBLOCKS 64

typedef __attribute__((ext_vector_type(8))) short bf16x8;
typedef __attribute__((ext_vector_type(4))) float f32x4;

static __device__ __forceinline__ unsigned short f2bf(float v) {
    __hip_bfloat16 h = __float2bfloat16(v);
    unsigned short b;
    __builtin_memcpy(&b, &h, 2);
    return b;
}
static __device__ __forceinline__ float bf2f(unsigned short b) {
    unsigned int u = ((unsigned int)b) << 16;
    float f;
    __builtin_memcpy(&f, &u, 4);
    return f;
}

// ---------------------------------------------------------------------------
// prep (64 blocks x 256): per block 16 codes. se[k] exact fp32 (ascending-d
// fmaf — must match vq_fix), eT[k][d] fp32, ehT/elT[k][d] bf16 hi/lo.
__global__ void vq_prep(const float* __restrict__ e,
                        float* __restrict__ se,
                        float* __restrict__ eT,
                        unsigned short* __restrict__ ehT,
                        unsigned short* __restrict__ elT,
                        int* __restrict__ ctrl) {
    __shared__ float tile[64][17];
    const int t = threadIdx.x;
    const int k0 = blockIdx.x * 16;
    if (blockIdx.x == 0 && t < 4) ctrl[t] = 0;
    #pragma unroll
    for (int i = 0; i < 4; ++i) {
        int idx = i * 256 + t;
        int d = idx >> 4, kk = idx & 15;
        tile[d][kk] = e[d * KCODE + k0 + kk];
    }
    __syncthreads();
    if (t < 16) {
        float s = 0.f;
        #pragma unroll
        for (int d = 0; d < 64; ++d) { float v = tile[d][t]; s = fmaf(v, v, s); }
        se[k0 + t] = s;
    }
    const int kk = t >> 4;           // code 0..15
    const int dg = (t & 15) * 4;     // dim chunk
    float v0 = tile[dg + 0][kk], v1 = tile[dg + 1][kk];
    float v2 = tile[dg + 2][kk], v3 = tile[dg + 3][kk];
    *(float4*)&eT[(size_t)(k0 + kk) * 64 + dg] = make_float4(v0, v1, v2, v3);
    unsigned short h0 = f2bf(v0), h1 = f2bf(v1), h2 = f2bf(v2), h3 = f2bf(v3);
    *(ushort4*)&ehT[(size_t)(k0 + kk) * 64 + dg] = make_ushort4(h0, h1, h2, h3);
    *(ushort4*)&elT[(size_t)(k0 + kk) * 64 + dg] =
        make_ushort4(f2bf(v0 - bf2f(h0)), f2bf(v1 - bf2f(h1)),
                     f2bf(v2 - bf2f(h2)), f2bf(v3 - bf2f(h3)));
}

// ---------------------------------------------------------------------------
__launch_bounds__(256, 2)
__global__ void vq_main(const float* __restrict__ x,
                        const float* __restrict__ se,
                        const float* __restrict__ eT,
                        const unsigned short* __restrict__ ehT,
                        const unsigned short* __restrict__ elT,
                        float* __restrict__ out,
                        float* __restrict__ lossAcc,
                        int* __restrict__ cnt,
                        int2* __restrict__ list) {
    __shared__ float Lb [64][65];
    __shared__ float Lb2[64][65];
    __shared__ int   Li [64][65];
    __shared__ int   rowIdx[64];
    __shared__ float wsum[4];

    const int t = threadIdx.x;
    const int lane = t & 63;
    const int w = t >> 6;                 // 0..3, this wave's K-slice
    const int quad = lane >> 4, l15 = lane & 15;
    const int rowBlk = blockIdx.x * 64;

    // ---- A fragments: 4 M-tiles (rows rowBlk..rowBlk+63), built in-register ----
    bf16x8 ah[4][2], al[4][2];
    #pragma unroll
    for (int mt = 0; mt < 4; ++mt) {
        #pragma unroll
        for (int ks = 0; ks < 2; ++ks) {
            const float4* ap = (const float4*)(x + (size_t)(rowBlk + mt * 16 + l15) * 64
                                               + ks * 32 + quad * 8);
            float4 a0 = ap[0], a1 = ap[1];
            float av[8] = {a0.x, a0.y, a0.z, a0.w, a1.x, a1.y, a1.z, a1.w};
            bf16x8 h, l;
            #pragma unroll
            for (int j = 0; j < 8; ++j) {
                unsigned short hb = f2bf(av[j]);
                h[j] = (short)hb;
                l[j] = (short)f2bf(av[j] - bf2f(hb));
            }
            ah[mt][ks] = h; al[mt][ks] = l;
        }
    }

    float sb[4][4], sb2[4][4];
    int   si[4][4];
    #pragma unroll
    for (int mt = 0; mt < 4; ++mt)
        #pragma unroll
        for (int r = 0; r < 4; ++r) { sb[mt][r] = 3.4e38f; sb2[mt][r] = 3.4e38f; si[mt][r] = 0; }

    // ---- B ring-4 register prefetch over this wave's 256 codes (16 tiles) ----
    const int cbase = w * 256;
    const size_t bStr = (size_t)64;
    bf16x8 h0[4], h1[4], l0[4], l1[4];
    float sen[4];
    #pragma unroll
    for (int p = 0; p < 4; ++p) {
        const int nl = cbase + p * 16 + l15;
        const bf16x8* hp = (const bf16x8*)(ehT + (size_t)nl * bStr + quad * 8);
        const bf16x8* lp = (const bf16x8*)(elT + (size_t)nl * bStr + quad * 8);
        h0[p] = hp[0]; h1[p] = hp[4]; l0[p] = lp[0]; l1[p] = lp[4];
        sen[p] = se[nl];
    }

    #pragma unroll 4
    for (int nt = 0; nt < 16; ++nt) {
        const int p = nt & 3;
        bf16x8 ch0 = h0[p], ch1 = h1[p], cl0 = l0[p], cl1 = l1[p];
        float cse = sen[p];
        {   // prefetch tile nt+4 (reads run into 64-code pad region of ws; never consumed)
            const int nl = cbase + (nt + 4) * 16 + l15;
            const bf16x8* hp = (const bf16x8*)(ehT + (size_t)nl * bStr + quad * 8);
            const bf16x8* lp = (const bf16x8*)(elT + (size_t)nl * bStr + quad * 8);
            h0[p] = hp[0]; h1[p] = hp[4]; l0[p] = lp[0]; l1[p] = lp[4];
            sen[p] = se[nl];
        }
        const int nl = cbase + nt * 16 + l15;
        #pragma unroll
        for (int mt = 0; mt < 4; ++mt) {
            f32x4 aA = {0.f, 0.f, 0.f, 0.f}, aB = {0.f, 0.f, 0.f, 0.f};
            aA = __builtin_amdgcn_mfma_f32_16x16x32_bf16(ah[mt][0], ch0, aA, 0, 0, 0);
            aB = __builtin_amdgcn_mfma_f32_16x16x32_bf16(ah[mt][1], ch1, aB, 0, 0, 0);
            aA = __builtin_amdgcn_mfma_f32_16x16x32_bf16(ah[mt][0], cl0, aA, 0, 0, 0);
            aB = __builtin_amdgcn_mfma_f32_16x16x32_bf16(ah[mt][1], cl1, aB, 0, 0, 0);
            aA = __builtin_amdgcn_mfma_f32_16x16x32_bf16(al[mt][0], ch0, aA, 0, 0, 0);
            aB = __builtin_amdgcn_mfma_f32_16x16x32_bf16(al[mt][1], ch1, aB, 0, 0, 0);
            #pragma unroll
            for (int r = 0; r < 4; ++r) {
                float key = fmaf(-2.f, aA[r] + aB[r], cse);   // se - 2*dot
                bool lt = key < sb[mt][r];                     // strict: earliest k wins
                sb2[mt][r] = fminf(sb2[mt][r], fmaxf(sb[mt][r], key));
                sb[mt][r]  = fminf(sb[mt][r], key);
                si[mt][r]  = lt ? nl : si[mt][r];
            }
        }
    }

    // ---- exchange candidates: row-local = mt*16+quad*4+r, col = w*16+l15 ----
    const int col = w * 16 + l15;
    #pragma unroll
    for (int mt = 0; mt < 4; ++mt)
        #pragma unroll
        for (int r = 0; r < 4; ++r) {
            int rr = mt * 16 + quad * 4 + r;
            Lb [rr][col] = sb [mt][r];
            Lb2[rr][col] = sb2[mt][r];
            Li [rr][col] = si [mt][r];
        }
    __syncthreads();

    // ---- per-row reduce over 64 candidates (wave 0) ----
    if (t < 64) {
        float B = Lb[t][0], B2 = Lb2[t][0];
        int I = Li[t][0];
        for (int c = 1; c < 64; ++c) {
            float b = Lb[t][c], b2 = Lb2[t][c];
            int i = Li[t][c];
            float nB2 = fminf(fminf(B2, b2), fmaxf(B, b));
            bool take = (b < B) || (b == B && i < I);
            B = take ? b : B;
            I = take ? i : I;
            B2 = nB2;
        }
        rowIdx[t] = I;
        if (B2 - B < MARGIN) {
            int p = atomicAdd(cnt, 1);
            list[p] = make_int2(rowBlk + t, I);
        }
    }
    __syncthreads();

    // ---- epilogue: wave w writes rows [w*16, w*16+16); lane: row w*16+l15 ----
    {
        const int rl = w * 16 + l15;
        const int idx = rowIdx[rl];
        const float4* qrow = (const float4*)(eT + (size_t)idx * 64 + quad * 16);
        const float4* xrow = (const float4*)(x + (size_t)(rowBlk + rl) * 64 + quad * 16);
        float4* orow = (float4*)(out + (size_t)(rowBlk + rl) * 64 + quad * 16);
        float lsum = 0.f;
        #pragma unroll
        for (int i = 0; i < 4; ++i) {
            float4 q = qrow[i];
            float4 xv = xrow[i];
            float4 o;
            float dx;
            dx = q.x - xv.x; o.x = xv.x + dx; lsum = fmaf(dx, dx, lsum);
            dx = q.y - xv.y; o.y = xv.y + dx; lsum = fmaf(dx, dx, lsum);
            dx = q.z - xv.z; o.z = xv.z + dx; lsum = fmaf(dx, dx, lsum);
            dx = q.w - xv.w; o.w = xv.w + dx; lsum = fmaf(dx, dx, lsum);
            orow[i] = o;
        }
        #pragma unroll
        for (int off = 32; off > 0; off >>= 1)
            lsum += __shfl_down(lsum, off, 64);
        if (lane == 0) wsum[w] = lsum;
    }
    __syncthreads();
    if (t == 0)
        atomicAdd(lossAcc, wsum[0] + wsum[1] + wsum[2] + wsum[3]);
}

// ---------------------------------------------------------------------------
// Exact fp32 re-score of flagged rows (replicates R1's absmax-0 math), patch
// out + loss; last block finalizes the loss scalar.
__global__ void vq_fix(const float* __restrict__ x,
                       const float* __restrict__ se,
                       const float* __restrict__ eT,
                       const int2* __restrict__ list,
                       const int* __restrict__ cnt,
                       float* __restrict__ lossAcc,
                       int* __restrict__ done,
                       float* __restrict__ out) {
    __shared__ float xs[64];
    __shared__ float cb[256];
    __shared__ int   ci[256];
    __shared__ int   newIdxS;
    const int t = threadIdx.x;
    const int n = *cnt;

    for (int i = blockIdx.x; i < n; i += gridDim.x) {
        int2 en = list[i];
        const int row = en.x, oldIdx = en.y;
        if (t < 64) xs[t] = x[(size_t)row * 64 + t];
        __syncthreads();

        float sx = 0.f;
        #pragma unroll
        for (int d = 0; d < 64; ++d) sx = fmaf(xs[d], xs[d], sx);

        float db = 3.4e38f; int di = 0;
        #pragma unroll
        for (int j = 0; j < 4; ++j) {
            int k = t * 4 + j;
            const float* ep = eT + (size_t)k * 64;
            float dot = 0.f;
            for (int d = 0; d < 64; ++d) dot = fmaf(xs[d], ep[d], dot);
            float t0 = sx + se[k];
            float dd = t0 - 2.0f * dot;                 // exact ref formula
            if (dd < db) { db = dd; di = k; }
        }
        cb[t] = db; ci[t] = di;
        __syncthreads();
        if (t == 0) {
            float B = cb[0]; int I = ci[0];
            for (int c = 1; c < 256; ++c)
                if (cb[c] < B) { B = cb[c]; I = ci[c]; }   // ascending k blocks
            newIdxS = I;
        }
        __syncthreads();

        const int ni = newIdxS;
        if (ni != oldIdx) {
            float delta = 0.f;
            if (t < 64) {
                float xv = xs[t];
                float qn = eT[(size_t)ni * 64 + t];
                float qo = eT[(size_t)oldIdx * 64 + t];
                float dn = qn - xv, dl = qo - xv;
                out[(size_t)row * 64 + t] = xv + dn;
                delta = dn * dn - dl * dl;
                #pragma unroll
                for (int off = 32; off > 0; off >>= 1)
                    delta += __shfl_down(delta, off, 64);
                if (t == 0) atomicAdd(lossAcc, delta);
            }
        }
        __syncthreads();
    }

    if (t == 0) {
        __threadfence();
        int fin = atomicAdd(done, 1);
        if (fin == gridDim.x - 1) {
            float s = atomicAdd(lossAcc, 0.0f);   // coherent read of final sum
            float m = s / (float)NELEM;
            out[NELEM] = 0.25f * m + m;
        }
    }
}

// ---------------------------------------------------------------------------
extern "C" void kernel_launch(void* const* d_in, const int* in_sizes, int n_in,
                              void* d_out, int out_size, void* d_ws, size_t ws_size,
                              hipStream_t stream) {
    const float* x = (const float*)d_in[0];
    const float* e = (const float*)d_in[1];
    float* out = (float*)d_out;
    float* ws  = (float*)d_ws;

    // ws layout (float offsets):
    //   [0..15]   ctrl: lossAcc, cnt, done, spare
    //   +64       se   [1088 used (64-code read pad); region to +1280]
    //   +1280     eT   [65536]
    //   +66816    ehT  [1088*64 ushort = 34816 f]
    //   +101632   elT  [1088*64 ushort = 34816 f]
    //   +136448   list [32768 int2 = 65536 f]
    float* lossAcc      = ws;
    int*   cnt          = (int*)(ws + 1);
    int*   done         = (int*)(ws + 2);
    float* se           = ws + 64;
    float* eT           = ws + 1280;
    unsigned short* ehT = (unsigned short*)(ws + 66816);
    unsigned short* elT = (unsigned short*)(ws + 101632);
    int2*  list         = (int2*)(ws + 136448);

    vq_prep<<<64, 256, 0, stream>>>(e, se, eT, ehT, elT, (int*)ws);
    vq_main<<<NROWS / 64, 256, 0, stream>>>(x, se, eT, ehT, elT, out, lossAcc, cnt, list);
    vq_fix<<<FIXBLOCKS, 256, 0, stream>>>(x, se, eT, list, cnt, lossAcc, done, out);
}